// Round 1
// baseline (1069.235 us; speedup 1.0000x reference)
//
#include <hip/hip_runtime.h>
#include <hip/hip_bf16.h>
#include <cstdint>
#include <cstddef>

// Problem constants (B,S,D) = (4,4096,2048)
#define BB   4
#define SS   4096
#define DD   2048
#define N1   6144       // 3*D
#define MM   16384      // B*S

typedef unsigned short ushort_t;
typedef __attribute__((ext_vector_type(8))) __bf16 bf16x8;
typedef __attribute__((ext_vector_type(4))) float f32x4;

__device__ __forceinline__ unsigned short f2bf(float f) {
    union { float f; unsigned u; } x; x.f = f;
    unsigned r = x.u + 0x7fffu + ((x.u >> 16) & 1u);   // RNE
    return (unsigned short)(r >> 16);
}
__device__ __forceinline__ float bf2f(unsigned short u) {
    union { unsigned u; float f; } x; x.u = ((unsigned)u) << 16;
    return x.f;
}

// ---------------- RoPE cos/sin tables: [S][512] ----------------
__global__ __launch_bounds__(1024) void rope_tables(float* __restrict__ ct, float* __restrict__ st) {
    int idx = blockIdx.x * 1024 + threadIdx.x;      // 4096*512 = 2M entries
    int s = idx >> 9, i = idx & 511;
    // inv_freq[i] = 10000^(-i/512)
    float inv = exp2f(-(float)i * (13.287712379549449f / 512.0f));
    float fr = (float)s * inv;
    float c, sn; sincosf(fr, &sn, &c);
    ct[idx] = c; st[idx] = sn;
}

// ---------------- transpose + f32->bf16 convert: out[C][R] = in[R][C] ----------------
__global__ __launch_bounds__(256) void transpose_cvt(const float* __restrict__ in, ushort_t* __restrict__ out,
                                                     int R, int C) {
    __shared__ float tile[32][33];
    int c0 = blockIdx.x * 32, r0 = blockIdx.y * 32;
    int tx = threadIdx.x, ty = threadIdx.y;          // (32,8)
    #pragma unroll
    for (int i = 0; i < 32; i += 8)
        tile[ty + i][tx] = in[(size_t)(r0 + ty + i) * C + c0 + tx];
    __syncthreads();
    #pragma unroll
    for (int i = 0; i < 32; i += 8)
        out[(size_t)(c0 + ty + i) * R + r0 + tx] = f2bf(tile[tx][ty + i]);
}

// ---------------- LayerNorm row -> bf16 h ----------------
__global__ __launch_bounds__(256) void ln_kernel(const float* __restrict__ X, const float* __restrict__ w,
                                                 const float* __restrict__ bv, ushort_t* __restrict__ h) {
    int row = blockIdx.x, tid = threadIdx.x;
    const float4* xr = (const float4*)(X + (size_t)row * DD);
    float4 v0 = xr[tid], v1 = xr[tid + 256];
    float sum = v0.x + v0.y + v0.z + v0.w + v1.x + v1.y + v1.z + v1.w;
    float sq  = v0.x*v0.x + v0.y*v0.y + v0.z*v0.z + v0.w*v0.w
              + v1.x*v1.x + v1.y*v1.y + v1.z*v1.z + v1.w*v1.w;
    #pragma unroll
    for (int off = 32; off > 0; off >>= 1) { sum += __shfl_down(sum, off); sq += __shfl_down(sq, off); }
    __shared__ float red[8];
    int lane = tid & 63, wid = tid >> 6;
    if (lane == 0) { red[wid] = sum; red[4 + wid] = sq; }
    __syncthreads();
    sum = red[0] + red[1] + red[2] + red[3];
    sq  = red[4] + red[5] + red[6] + red[7];
    float mu = sum * (1.0f / DD);
    float var = sq * (1.0f / DD) - mu * mu;
    float rstd = rsqrtf(var + 1e-5f);
    const float4* wr4 = (const float4*)w; const float4* br4 = (const float4*)bv;
    float4 w0 = wr4[tid], w1 = wr4[tid + 256], b0 = br4[tid], b1 = br4[tid + 256];
    ushort4 o;
    o.x = f2bf((v0.x - mu) * rstd * w0.x + b0.x);
    o.y = f2bf((v0.y - mu) * rstd * w0.y + b0.y);
    o.z = f2bf((v0.z - mu) * rstd * w0.z + b0.z);
    o.w = f2bf((v0.w - mu) * rstd * w0.w + b0.w);
    *(ushort4*)(h + (size_t)row * DD + tid * 4) = o;
    o.x = f2bf((v1.x - mu) * rstd * w1.x + b1.x);
    o.y = f2bf((v1.y - mu) * rstd * w1.y + b1.y);
    o.z = f2bf((v1.z - mu) * rstd * w1.z + b1.z);
    o.w = f2bf((v1.w - mu) * rstd * w1.w + b1.w);
    *(ushort4*)(h + (size_t)row * DD + 1024 + tid * 4) = o;
}

// ---------------- GEMM: C[M,N] = A[M,K](bf16) * BT[N,K]^T(bf16), m97 structure ----------------
// MODE 0: outb = bf16(acc + bias[n])
// MODE 1: outf = acc + bias[n] + Xres[row*N+n]   (f32)
template <int MODE>
__global__ __launch_bounds__(256)
void gemm_bt(const ushort_t* __restrict__ A, const ushort_t* __restrict__ BT,
             const float* __restrict__ bias, const float* __restrict__ Xres,
             ushort_t* __restrict__ outb, float* __restrict__ outf,
             int K, int N) {
    __shared__ ushort_t As[2][128 * 32];
    __shared__ ushort_t Bs[2][128 * 32];
    const int tid = threadIdx.x;
    const int lane = tid & 63;
    const int wid = tid >> 6;
    const int wr = wid >> 1, wc = wid & 1;
    const int row0 = blockIdx.y * 128;
    const int col0 = blockIdx.x * 128;

    f32x4 acc[4][4] = {};

    auto stage = [&](int t, int buf) {
        const int k0 = t * 32;
        #pragma unroll
        for (int i = 0; i < 2; ++i) {
            const int sub = wid * 2 + i;
            const int r = sub * 16 + (lane >> 2);
            const int kk = (lane & 3) * 8;
            const ushort_t* srcA = A + (size_t)(row0 + r) * K + k0 + kk;
            __builtin_amdgcn_global_load_lds(
                (const __attribute__((address_space(1))) unsigned int*)srcA,
                (__attribute__((address_space(3))) unsigned int*)&As[buf][sub * 512], 16, 0, 0);
            const ushort_t* srcB = BT + (size_t)(col0 + r) * K + k0 + kk;
            __builtin_amdgcn_global_load_lds(
                (const __attribute__((address_space(1))) unsigned int*)srcB,
                (__attribute__((address_space(3))) unsigned int*)&Bs[buf][sub * 512], 16, 0, 0);
        }
    };

    const int T = K >> 5;
    stage(0, 0);
    for (int t = 0; t < T; ++t) {
        const int cur = t & 1;
        if (t + 1 < T) stage(t + 1, cur ^ 1);
        __syncthreads();                 // compiler drains vmcnt(0) here -> tile t ready
        const int ar = (wr * 64 + (lane & 15)) * 32 + ((lane >> 4) * 8);
        const int br = (wc * 64 + (lane & 15)) * 32 + ((lane >> 4) * 8);
        bf16x8 a[4], b[4];
        #pragma unroll
        for (int mi = 0; mi < 4; ++mi) a[mi] = *(const bf16x8*)&As[cur][ar + mi * 16 * 32];
        #pragma unroll
        for (int ni = 0; ni < 4; ++ni) b[ni] = *(const bf16x8*)&Bs[cur][br + ni * 16 * 32];
        #pragma unroll
        for (int mi = 0; mi < 4; ++mi)
            #pragma unroll
            for (int ni = 0; ni < 4; ++ni)
                acc[mi][ni] = __builtin_amdgcn_mfma_f32_16x16x32_bf16(a[mi], b[ni], acc[mi][ni], 0, 0, 0);
        __syncthreads();                 // protect buf cur before it is re-staged next iter
    }

    // epilogue: C/D layout col = lane&15, row = (lane>>4)*4 + j
    const int orow0 = row0 + wr * 64;
    const int ocol0 = col0 + wc * 64;
    #pragma unroll
    for (int mi = 0; mi < 4; ++mi) {
        #pragma unroll
        for (int ni = 0; ni < 4; ++ni) {
            const int col = ocol0 + ni * 16 + (lane & 15);
            const float bc = bias[col];
            #pragma unroll
            for (int j = 0; j < 4; ++j) {
                const int row = orow0 + mi * 16 + (lane >> 4) * 4 + j;
                float v = acc[mi][ni][j] + bc;
                if (MODE == 0) {
                    outb[(size_t)row * N + col] = f2bf(v);
                } else {
                    outf[(size_t)row * N + col] = v + Xres[(size_t)row * N + col];
                }
            }
        }
    }
}

// ---------------- RoPE in place on Q and K halves of qkv ----------------
__global__ __launch_bounds__(256) void rope_apply(ushort_t* __restrict__ qkv,
                                                  const float* __restrict__ ct, const float* __restrict__ st) {
    int row = blockIdx.x, tid = threadIdx.x;
    int s = row & (SS - 1);
    ushort_t* base = qkv + (size_t)row * N1;
    const float* c = ct + (size_t)s * 512;
    const float* sn = st + (size_t)s * 512;
    #pragma unroll
    for (int p = tid; p < 1024; p += 256) {
        int part = (p >> 9) * DD;        // p<512 -> Q(+0), else K(+2048)
        int pp = p & 511;
        float cv = c[pp], sv = sn[pp];
        unsigned* ptr = (unsigned*)(base + part + 2 * pp);
        unsigned u = *ptr;
        float x1 = bf2f((unsigned short)(u & 0xffff));
        float x2 = bf2f((unsigned short)(u >> 16));
        float o1 = x1 * cv - x2 * sv;
        float o2 = x2 * cv + x1 * sv;
        *ptr = (unsigned)f2bf(o1) | ((unsigned)f2bf(o2) << 16);
    }
}

// ---------------- 1/||K_row|| ----------------
__global__ __launch_bounds__(256) void knorm(const ushort_t* __restrict__ qkv, float* __restrict__ invn) {
    int row = blockIdx.x, tid = threadIdx.x;
    const ushort_t* k = qkv + (size_t)row * N1 + DD;
    ushort4 u0 = ((const ushort4*)k)[tid], u1 = ((const ushort4*)k)[tid + 256];
    float sq = 0.f;
    float a;
    a = bf2f(u0.x); sq += a * a;  a = bf2f(u0.y); sq += a * a;
    a = bf2f(u0.z); sq += a * a;  a = bf2f(u0.w); sq += a * a;
    a = bf2f(u1.x); sq += a * a;  a = bf2f(u1.y); sq += a * a;
    a = bf2f(u1.z); sq += a * a;  a = bf2f(u1.w); sq += a * a;
    #pragma unroll
    for (int off = 32; off > 0; off >>= 1) sq += __shfl_down(sq, off);
    __shared__ float red[4];
    int lane = tid & 63, wid = tid >> 6;
    if (lane == 0) red[wid] = sq;
    __syncthreads();
    if (tid == 0) invn[row] = rsqrtf(red[0] + red[1] + red[2] + red[3]);
}

__global__ __launch_bounds__(1024) void zerof(float* __restrict__ p, int n) {
    int i = blockIdx.x * 1024 + threadIdx.x;
    if (i < n) p[i] = 0.f;
}

// ---------------- A[b][d] = sum_s K_hat[b,s,d] * V[b,s,d] ----------------
__global__ __launch_bounds__(256) void areduce(const ushort_t* __restrict__ qkv,
                                               const float* __restrict__ invn, float* __restrict__ Aacc) {
    int b = blockIdx.z, tid = threadIdx.x;
    int d = blockIdx.y * 256 + tid;
    int row0 = b * SS + blockIdx.x * 64;
    float acc = 0.f;
    #pragma unroll 4
    for (int i = 0; i < 64; ++i) {
        int row = row0 + i;
        const ushort_t* p = qkv + (size_t)row * N1 + DD + d;   // K at +DD, V at +2*DD
        acc += bf2f(p[0]) * bf2f(p[DD]) * invn[row];
    }
    atomicAdd(&Aacc[b * DD + d], acc);
}

// ---------------- AQ[b,s,d] = A[b,d] * Q_roped[b,s,d] (bf16) ----------------
__global__ __launch_bounds__(256) void aq_kernel(const ushort_t* __restrict__ qkv,
                                                 const float* __restrict__ Aacc, ushort_t* __restrict__ AQ) {
    const size_t total = (size_t)MM * (DD / 8);
    for (size_t i = (size_t)blockIdx.x * 256 + threadIdx.x; i < total; i += (size_t)gridDim.x * 256) {
        const size_t row = i >> 8;               // 256 groups of 8 per row
        const int d = (int)(i & 255) * 8;
        const int bi = (int)(row >> 12);         // row / 4096
        uint4 u = *(const uint4*)(qkv + row * N1 + d);
        const float* Ab = Aacc + bi * DD + d;
        unsigned uu[4] = { u.x, u.y, u.z, u.w };
        unsigned oo[4];
        #pragma unroll
        for (int j = 0; j < 4; ++j) {
            float lo = bf2f((unsigned short)(uu[j] & 0xffff)) * Ab[2 * j];
            float hi = bf2f((unsigned short)(uu[j] >> 16)) * Ab[2 * j + 1];
            oo[j] = (unsigned)f2bf(lo) | ((unsigned)f2bf(hi) << 16);
        }
        uint4 o; o.x = oo[0]; o.y = oo[1]; o.z = oo[2]; o.w = oo[3];
        *(uint4*)(AQ + row * DD + d) = o;
    }
}

extern "C" void kernel_launch(void* const* d_in, const int* in_sizes, int n_in,
                              void* d_out, int out_size, void* d_ws, size_t ws_size,
                              hipStream_t stream) {
    (void)in_sizes; (void)n_in; (void)out_size; (void)ws_size;
    const float* X     = (const float*)d_in[0];
    const float* ln_w  = (const float*)d_in[1];
    const float* ln_b  = (const float*)d_in[2];
    const float* W_in  = (const float*)d_in[3];
    const float* b_in  = (const float*)d_in[4];
    const float* W_out = (const float*)d_in[5];
    const float* b_out = (const float*)d_in[6];
    float* out = (float*)d_out;

    char* w = (char*)d_ws;
    auto take = [&](size_t bytes) { char* p = w; w += (bytes + 255) & ~(size_t)255; return p; };
    float*    costab = (float*)take((size_t)SS * 512 * 4);
    float*    sintab = (float*)take((size_t)SS * 512 * 4);
    ushort_t* WTin   = (ushort_t*)take((size_t)N1 * DD * 2);
    ushort_t* WTout  = (ushort_t*)take((size_t)DD * DD * 2);
    ushort_t* hbuf   = (ushort_t*)take((size_t)MM * DD * 2);   // reused as AQ after GEMM1
    ushort_t* qkv    = (ushort_t*)take((size_t)MM * N1 * 2);
    float*    invn   = (float*)take((size_t)MM * 4);
    float*    Aacc   = (float*)take((size_t)BB * DD * 4);
    ushort_t* AQ     = hbuf;

    rope_tables<<<(SS * 512) / 1024, 1024, 0, stream>>>(costab, sintab);
    transpose_cvt<<<dim3(N1 / 32, DD / 32), dim3(32, 8), 0, stream>>>(W_in, WTin, DD, N1);
    transpose_cvt<<<dim3(DD / 32, DD / 32), dim3(32, 8), 0, stream>>>(W_out, WTout, DD, DD);
    ln_kernel<<<MM, 256, 0, stream>>>(X, ln_w, ln_b, hbuf);
    gemm_bt<0><<<dim3(N1 / 128, MM / 128), 256, 0, stream>>>(hbuf, WTin, b_in, nullptr, qkv, nullptr, DD, N1);
    rope_apply<<<MM, 256, 0, stream>>>(qkv, costab, sintab);
    knorm<<<MM, 256, 0, stream>>>(qkv, invn);
    zerof<<<(BB * DD + 1023) / 1024, 1024, 0, stream>>>(Aacc, BB * DD);
    areduce<<<dim3(64, DD / 256, BB), 256, 0, stream>>>(qkv, invn, Aacc);
    aq_kernel<<<2048, 256, 0, stream>>>(qkv, Aacc, AQ);
    gemm_bt<1><<<dim3(DD / 128, MM / 128), 256, 0, stream>>>(AQ, WTout, b_out, X, nullptr, out, DD, DD);
}